// Round 5
// baseline (1326.263 us; speedup 1.0000x reference)
//
#include <hip/hip_runtime.h>
#include <math.h>

// ContextAwareFlowRouter: B=4,S=1024,IN=OUT=128,P=16, D=16384, MAX_SEQ=4096
// fp32 bulk flow values + fp64-exact top-k boundary resolution on a small
// candidate list (mask provably identical to the fp64 numpy reference).
// Round 5: flow = 4 tokens/block @ 1024 thr (halves L2 pattern traffic,
// doubles FMA reuse per pattern load).
#define S_   1024
#define D_   16384
#define CAPL 512   // candidate list capacity per token
#define NB   512   // histogram buckets per token (64/octave, 8 octaves)

typedef float v4f __attribute__((ext_vector_type(4)));

__device__ __forceinline__ double gelu64(double v) {
    return 0.5 * v * (1.0 + erf(v * 0.70710678118654752440));
}
__device__ __forceinline__ double sigmoid64(double z) {
    return 1.0 / (1.0 + exp(-z));
}
__device__ __forceinline__ float rfl(float x) {   // force uniform -> SGPR
    return __uint_as_float(__builtin_amdgcn_readfirstlane(__float_as_uint(x)));
}

// ---------------- kernel 1: selector softmax + intensity (fp64 math) -------
// 2048 blocks x 256 thr; 2 tokens/block; dots split across lanes.
__global__ __launch_bounds__(256) void mlp_kernel(
    const float* __restrict__ x, const float* __restrict__ ctx,
    const float* __restrict__ w_sel1, const float* __restrict__ b_sel1,
    const float* __restrict__ w_sel2, const float* __restrict__ b_sel2,
    const float* __restrict__ w_int1, const float* __restrict__ b_int1,
    const float* __restrict__ w_int2, const float* __restrict__ b_int2,
    double* __restrict__ pw64, float* __restrict__ pw32,
    double* __restrict__ it64, float* __restrict__ it32)
{
    __shared__ double comb[2][256];
    __shared__ double h1[2][32];
    __shared__ double ipart[2][2];
    const int tid = threadIdx.x;
    const int tok0 = blockIdx.x * 2;
    const int t = tid >> 7, local = tid & 127;

    for (int r = 0; r < 2; ++r) {
        int idx = tid + r * 256;
        int tk = idx >> 8, i = idx & 255;
        comb[tk][i] = (double)((i < 128) ? x[(tok0 + tk) * 128 + i]
                                         : ctx[(tok0 + tk) * 128 + (i - 128)]);
    }
    __syncthreads();

    {   // sel1: 32 units x 4 slices of 64
        int u = local >> 2, sl = local & 3;
        int i0 = sl * 64;
        double s0 = (sl == 0) ? (double)b_sel1[u] : 0.0, s1 = 0.0;
        for (int i = 0; i < 64; i += 2) {
            s0 = fma(comb[t][i0 + i],     (double)w_sel1[(i0 + i) * 32 + u],     s0);
            s1 = fma(comb[t][i0 + i + 1], (double)w_sel1[(i0 + i + 1) * 32 + u], s1);
        }
        double s = s0 + s1;
        s += __shfl_xor(s, 1);
        s += __shfl_xor(s, 2);
        if (sl == 0) h1[t][u] = gelu64(s);
    }
    {   // int1: 64 units x 2 slices of 128; then reduce 64 units
        int u = local >> 1, sl = local & 1;
        int i0 = sl * 128;
        double a0 = (sl == 0) ? (double)b_int1[u] : 0.0, a1 = 0.0, a2 = 0.0, a3 = 0.0;
        for (int i = 0; i < 128; i += 4) {
            a0 = fma(comb[t][i0 + i],     (double)w_int1[(i0 + i) * 64 + u],     a0);
            a1 = fma(comb[t][i0 + i + 1], (double)w_int1[(i0 + i + 1) * 64 + u], a1);
            a2 = fma(comb[t][i0 + i + 2], (double)w_int1[(i0 + i + 2) * 64 + u], a2);
            a3 = fma(comb[t][i0 + i + 3], (double)w_int1[(i0 + i + 3) * 64 + u], a3);
        }
        double s = (a0 + a1) + (a2 + a3);
        s += __shfl_xor(s, 1);
        double val = (sl == 0) ? gelu64(s) * (double)w_int2[u] : 0.0;
        for (int off = 2; off <= 32; off <<= 1)
            val += __shfl_xor(val, off);
        val += __shfl_xor(val, 1);   // sl==1 lanes carry 0; each unit counted once
        if ((local & 63) == 0) ipart[t][local >> 6] = val;
    }
    __syncthreads();

    if (tid < 32) {   // sel2 + softmax over P=16
        int t2 = tid >> 4, u = tid & 15;
        double z = (double)b_sel2[u];
        for (int j = 0; j < 32; ++j)
            z = fma(h1[t2][j], (double)w_sel2[j * 16 + u], z);
        double m = z;
        for (int off = 8; off >= 1; off >>= 1) m = fmax(m, __shfl_xor(m, off));
        double e = exp(z - m);
        double ssum = e;
        for (int off = 8; off >= 1; off >>= 1) ssum += __shfl_xor(ssum, off);
        double pwv = e / ssum;
        pw64[(tok0 + t2) * 16 + u] = pwv;
        pw32[(tok0 + t2) * 16 + u] = (float)pwv;
    } else if (tid < 34) {   // intensity finish
        int t3 = tid - 32;
        double iv = sigmoid64(ipart[t3][0] + ipart[t3][1] + (double)b_int2[0]);
        it64[tok0 + t3] = iv;
        it32[tok0 + t3] = (float)iv;
    }
}

// ---------------- kernel 2a: x.mean(axis=1) partial sums -------------------
__global__ __launch_bounds__(256) void win_part_kernel(
    const float* __restrict__ x, double* __restrict__ wpart)
{
    __shared__ double red[2][128];
    const int tid = threadIdx.x;
    const int b = blockIdx.x >> 4, chunk = blockIdx.x & 15;
    int i = tid & 127, h = tid >> 7;
    double a0 = 0.0, a1 = 0.0;
    int s0 = b * S_ + chunk * 64 + h * 32;
    for (int j = 0; j < 32; j += 2) {
        a0 += (double)x[(s0 + j) * 128 + i];
        a1 += (double)x[(s0 + j + 1) * 128 + i];
    }
    red[h][i] = a0 + a1;
    __syncthreads();
    if (tid < 128)
        wpart[(b * 16 + chunk) * 128 + tid] = red[0][tid] + red[1][tid];
}

// ---------------- kernel 2b: finish window MLP -----------------------------
__global__ __launch_bounds__(256) void win_fin_kernel(
    const double* __restrict__ wpart,
    const float* __restrict__ w_win1, const float* __restrict__ b_win1,
    const float* __restrict__ w_win2, const float* __restrict__ b_win2,
    double* __restrict__ win_out)
{
    __shared__ double xm[4][128];
    const int tid = threadIdx.x;
    const int b = tid >> 6, lane = tid & 63;
    for (int r = 0; r < 2; ++r) {
        int i = lane + r * 64;
        double s = 0.0;
        for (int c = 0; c < 16; ++c)
            s += wpart[(b * 16 + c) * 128 + i];
        xm[b][i] = s * (1.0 / 1024.0);
    }
    __syncthreads();
    {
        int u = lane;
        double s0 = (double)b_win1[u], s1 = 0.0;
        for (int i = 0; i < 128; i += 2) {
            s0 = fma(xm[b][i],     (double)w_win1[i * 64 + u],       s0);
            s1 = fma(xm[b][i + 1], (double)w_win1[(i + 1) * 64 + u], s1);
        }
        double c = gelu64(s0 + s1) * (double)w_win2[u];
        for (int off = 32; off >= 1; off >>= 1) c += __shfl_xor(c, off);
        if (lane == 0)
            win_out[b] = sigmoid64(c + (double)b_win2[0]) * 3840.0 + 256.0;
    }
}

// ---------------- kernel 3: fp32 flow + histogram top-k + masked write -----
// 1024 blocks x 1024 thr; 4 tokens/block, 16 fp32 values/thread/token.
__global__ __launch_bounds__(1024, 4) void flow_kernel(
    const float* __restrict__ patterns,
    const double* __restrict__ pw64, const float* __restrict__ pw32,
    const double* __restrict__ it64, const float* __restrict__ it32,
    const double* __restrict__ win,
    float* __restrict__ out)
{
    __shared__ unsigned hist[4][NB];       // 8 KB
    __shared__ unsigned flagBits[4][512];  // 8 KB
    __shared__ unsigned listIdx[4][CAPL];  // 8 KB
    __shared__ double listVal[4][CAPL];    // 16 KB
    __shared__ float smax[4][16];
    __shared__ int sred[16];
    __shared__ int bcastB[4];
    __shared__ unsigned listCnt[4];

    const int tid = threadIdx.x;
    const int lane = tid & 63, wv = tid >> 6;
    const int t0 = blockIdx.x * 4;

    // zero LDS (hist + flags + counters)
    for (int r = tid; r < 4 * NB; r += 1024) hist[r >> 9][r & (NB - 1)] = 0;
    for (int r = tid; r < 2048; r += 1024) flagBits[r >> 9][r & 511] = 0;
    if (tid < 4) listCnt[tid] = 0;

    // k = max(1, floor(16384 * 0.1 * mean(window/4096)))  (np fp64 order)
    double w0 = win[0] * (1.0 / 4096.0), w1 = win[1] * (1.0 / 4096.0);
    double w2 = win[2] * (1.0 / 4096.0), w3 = win[3] * (1.0 / 4096.0);
    double mean = (((w0 + w1) + w2) + w3) * 0.25;
    double kd = floor(16384.0 * (0.1 * mean));
    int k = (kd < 1.0) ? 1 : (int)kd;

    float qw[4][16], it[4];
#pragma unroll
    for (int t = 0; t < 4; ++t) {
#pragma unroll
        for (int p = 0; p < 16; ++p)
            qw[t][p] = rfl(pw32[(t0 + t) * 16 + p]);
        it[t] = rfl(it32[t0 + t]);
    }

    const v4f* pat4 = (const v4f*)patterns;
    v4f v[4][4];   // [token][chunk]
#pragma unroll
    for (int c = 0; c < 4; ++c) {
        int grp = c * 1024 + tid;
        v4f a0 = (v4f)(0.0f), a1 = (v4f)(0.0f), a2 = (v4f)(0.0f), a3 = (v4f)(0.0f);
#pragma unroll
        for (int p = 0; p < 16; ++p) {
            v4f pp = pat4[p * 4096 + grp];
            a0 += qw[0][p] * pp;
            a1 += qw[1][p] * pp;
            a2 += qw[2][p] * pp;
            a3 += qw[3][p] * pp;
        }
        v[0][c] = a0 * it[0];
        v[1][c] = a1 * it[1];
        v[2][c] = a2 * it[2];
        v[3][c] = a3 * it[3];
    }

    // per-token max |v|
    float mx[4];
#pragma unroll
    for (int t = 0; t < 4; ++t) {
        float m = 0.0f;
#pragma unroll
        for (int c = 0; c < 4; ++c)
            m = fmaxf(m, fmaxf(fmaxf(fabsf(v[t][c].x), fabsf(v[t][c].y)),
                               fmaxf(fabsf(v[t][c].z), fabsf(v[t][c].w))));
        for (int off = 32; off >= 1; off >>= 1)
            m = fmaxf(m, __shfl_xor(m, off));
        if (lane == 0) smax[t][wv] = m;
        mx[t] = m;
    }
    __syncthreads();   // #1: covers zeroing + smax
    int base[4];
#pragma unroll
    for (int t = 0; t < 4; ++t) {
        float m = smax[t][0];
#pragma unroll
        for (int w = 1; w < 16; ++w) m = fmaxf(m, smax[t][w]);
        mx[t] = m;
        int b = (int)(__float_as_uint(m) >> 17) - (NB - 1);
        base[t] = (b < 0) ? 0 : b;
    }

    // histogram (skip underflow bucket 0 — never contains the threshold)
#pragma unroll
    for (int t = 0; t < 4; ++t) {
#pragma unroll
        for (int c = 0; c < 4; ++c) {
#pragma unroll
            for (int q = 0; q < 4; ++q) {
                int b = (int)(__float_as_uint(fabsf(v[t][c][q])) >> 17) - base[t];
                if (b > 0) atomicAdd(&hist[t][b > NB - 1 ? NB - 1 : b], 1u);
            }
        }
    }
    __syncthreads();   // #2

    // waves 0..3: suffix-scan to find bucket B = bucket of k-th largest
    if (wv < 4) {
        int t = wv;
        int sum8 = 0;
#pragma unroll
        for (int j = 0; j < 8; ++j) sum8 += (int)hist[t][lane * 8 + j];
        int suffix = sum8;
        for (int off = 1; off <= 32; off <<= 1) {
            int other = __shfl_down(suffix, off);
            if (lane + off < 64) suffix += other;
        }
        int sufNext = __shfl_down(suffix, 1);
        if (lane == 63) sufNext = 0;
        unsigned long long msk = __ballot(suffix >= k);
        int Lstar = (msk == 0) ? 0 : (63 - __clzll(msk));
        if (lane == Lstar) {
            int cnt = sufNext, B = Lstar * 8;
            for (int j = 7; j >= 0; --j) {
                cnt += (int)hist[t][Lstar * 8 + j];
                if (cnt >= k) { B = Lstar * 8 + j; break; }
            }
            bcastB[t] = B;
        }
    }
    __syncthreads();   // #3

    float loCut[4], hiCut[4];
#pragma unroll
    for (int t = 0; t < 4; ++t) {
        int B = bcastB[t];
        float loF = (B + base[t]) ? __uint_as_float((unsigned)(B + base[t]) << 17) : 0.0f;
        float hiF = __uint_as_float((unsigned)(B + base[t] + 1) << 17);
        float E = 3e-6f * it[t];   // bounds |v32 - a64|
        loCut[t] = loF - 2.0f * E;
        hiCut[t] = hiF + 2.0f * E;
    }

    // sure-in count + candidate collection (ns <= 16 per token per thread)
    int nsPack = 0;
#pragma unroll
    for (int t = 0; t < 4; ++t) {
        int ns = 0;
#pragma unroll
        for (int c = 0; c < 4; ++c) {
#pragma unroll
            for (int q = 0; q < 4; ++q) {
                unsigned e = (unsigned)(4 * (c * 1024 + tid) + q);
                float a = fabsf(v[t][c][q]);
                if (a >= hiCut[t]) ns++;
                else if (a >= loCut[t]) {
                    unsigned pos = atomicAdd(&listCnt[t], 1u);
                    if (pos < CAPL) listIdx[t][pos] = e;
                }
            }
        }
        nsPack |= ns << (8 * t);
    }
#pragma unroll
    for (int off = 32; off >= 1; off >>= 1) nsPack += __shfl_xor(nsPack, off);
    if (lane == 0) sred[wv] = nsPack;
    __syncthreads();   // #4
    // per-wave sums <= 64*16=1024 per byte-field... overflow! sum fields separately
    int m[4], cn[4];
    {
        int tot0 = 0, tot1 = 0, tot2 = 0, tot3 = 0;
#pragma unroll
        for (int w = 0; w < 16; ++w) {
            int s = sred[w];
            tot0 += (s)       & 0x3ff;   // per-wave field <= 64*16=1024 fits 11 bits?
            tot1 += (s >> 8)  & 0x3ff;
            tot2 += (s >> 16) & 0x3ff;
            tot3 += (s >> 24) & 0xff;
        }
        // NOTE: per-wave per-token sure-count <= 64 lanes * 16 = 1024 > 255:
        // byte fields can overflow — handled below by recomputing safely.
        m[0] = tot0; m[1] = tot1; m[2] = tot2; m[3] = tot3;
    }
    // SAFE RECOMPUTE of sure counts via per-token reduction (overflow-proof):
    {
#pragma unroll
        for (int t = 0; t < 4; ++t) {
            int ns = 0;
#pragma unroll
            for (int c = 0; c < 4; ++c) {
#pragma unroll
                for (int q = 0; q < 4; ++q)
                    ns += (fabsf(v[t][c][q]) >= hiCut[t]);
            }
#pragma unroll
            for (int off = 32; off >= 1; off >>= 1) ns += __shfl_xor(ns, off);
            if (lane == 0) sred[wv] = ns;
            __syncthreads();
            int tot = 0;
#pragma unroll
            for (int w = 0; w < 16; ++w) tot += sred[w];
            m[t] = k - tot;
            __syncthreads();
        }
    }
#pragma unroll
    for (int t = 0; t < 4; ++t)
        cn[t] = (int)(listCnt[t] < CAPL ? listCnt[t] : CAPL);

    // fp64-exact values for candidates (matches np ranking to ~1e-15)
#pragma unroll
    for (int t = 0; t < 4; ++t) {
        if (tid < cn[t]) {
            unsigned idx = listIdx[t][tid];
            const double* pwp = pw64 + (size_t)(t0 + t) * 16;
            double itt = it64[t0 + t];
            double s = 0.0;
#pragma unroll
            for (int p = 0; p < 16; ++p)
                s = fma(pwp[p], (double)patterns[p * D_ + idx], s);
            listVal[t][tid] = fabs(s * itt);
        }
    }
    __syncthreads();   // #5
    // rank within list; keep iff (#strictly-greater) < m   [tie-correct]
#pragma unroll
    for (int t = 0; t < 4; ++t) {
        if (tid < cn[t]) {
            double my = listVal[t][tid];
            int r = 0;
            for (int j = 0; j < cn[t]; ++j) r += (listVal[t][j] > my);
            if (r < m[t]) {
                unsigned idx = listIdx[t][tid];
                atomicOr(&flagBits[t][idx >> 5], 1u << (idx & 31));
            }
        }
    }
    __syncthreads();   // #6

    // masked write
#pragma unroll
    for (int t = 0; t < 4; ++t) {
        v4f* op = (v4f*)(out + (size_t)(t0 + t) * D_);
#pragma unroll
        for (int c = 0; c < 4; ++c) {
            int grp = c * 1024 + tid;
            v4f r;
#pragma unroll
            for (int q = 0; q < 4; ++q) {
                unsigned e = (unsigned)(4 * grp + q);
                float av = fabsf(v[t][c][q]);
                bool keep = (av >= hiCut[t]);
                if (!keep && av >= loCut[t])
                    keep = (flagBits[t][e >> 5] >> (e & 31)) & 1u;
                r[q] = keep ? v[t][c][q] : 0.0f;
            }
            __builtin_nontemporal_store(r, &op[grp]);
        }
    }
}

extern "C" void kernel_launch(void* const* d_in, const int* in_sizes, int n_in,
                              void* d_out, int out_size, void* d_ws, size_t ws_size,
                              hipStream_t stream) {
    const float* x        = (const float*)d_in[0];
    const float* ctx      = (const float*)d_in[1];
    const float* patterns = (const float*)d_in[2];
    const float* w_sel1   = (const float*)d_in[3];
    const float* b_sel1   = (const float*)d_in[4];
    const float* w_sel2   = (const float*)d_in[5];
    const float* b_sel2   = (const float*)d_in[6];
    const float* w_int1   = (const float*)d_in[7];
    const float* b_int1   = (const float*)d_in[8];
    const float* w_int2   = (const float*)d_in[9];
    const float* b_int2   = (const float*)d_in[10];
    const float* w_win1   = (const float*)d_in[11];
    const float* b_win1   = (const float*)d_in[12];
    const float* w_win2   = (const float*)d_in[13];
    const float* b_win2   = (const float*)d_in[14];

    double* ws    = (double*)d_ws;
    double* win   = ws;                   // 8 doubles reserved
    double* pw64  = ws + 8;               // 65536
    double* it64  = pw64 + 65536;         // 4096
    double* wpart = it64 + 4096;          // 8192
    float*  pw32  = (float*)(wpart + 8192);  // 65536 floats
    float*  it32  = pw32 + 65536;            // 4096 floats
    float*  out   = (float*)d_out;

    hipLaunchKernelGGL(mlp_kernel, dim3(2048), dim3(256), 0, stream,
                       x, ctx, w_sel1, b_sel1, w_sel2, b_sel2,
                       w_int1, b_int1, w_int2, b_int2, pw64, pw32, it64, it32);
    hipLaunchKernelGGL(win_part_kernel, dim3(64), dim3(256), 0, stream, x, wpart);
    hipLaunchKernelGGL(win_fin_kernel, dim3(1), dim3(256), 0, stream,
                       wpart, w_win1, b_win1, w_win2, b_win2, win);
    hipLaunchKernelGGL(flow_kernel, dim3(1024), dim3(1024), 0, stream,
                       patterns, pw64, pw32, it64, it32, win, out);
}

// Round 6
// 441.259 us; speedup vs baseline: 3.0056x; 3.0056x over previous
//
#include <hip/hip_runtime.h>
#include <math.h>

// ContextAwareFlowRouter: B=4,S=1024,IN=OUT=128,P=16, D=16384, MAX_SEQ=4096
// fp32 bulk flow values + fp64-exact top-k boundary resolution on a small
// candidate list (mask provably identical to the fp64 numpy reference).
// Round 6: revert to round-4 T=2@512 flow (r5's T=4 spilled to scratch);
// value loop restructured into explicit 8-load batches for latency hiding.
// mlp intensity path in fp32 (uniform per-token scale -> ranking-invariant).
#define S_   1024
#define D_   16384
#define CAPL 512   // candidate list capacity per token
#define NB   512   // histogram buckets per token (64/octave, 8 octaves)

typedef float v4f __attribute__((ext_vector_type(4)));

__device__ __forceinline__ double gelu64(double v) {
    return 0.5 * v * (1.0 + erf(v * 0.70710678118654752440));
}
__device__ __forceinline__ float gelu32(float v) {
    return 0.5f * v * (1.0f + erff(v * 0.70710678f));
}
__device__ __forceinline__ double sigmoid64(double z) {
    return 1.0 / (1.0 + exp(-z));
}
__device__ __forceinline__ float sigmoid32(float z) {
    return 1.0f / (1.0f + expf(-z));
}
__device__ __forceinline__ float rfl(float x) {   // force uniform -> SGPR
    return __uint_as_float(__builtin_amdgcn_readfirstlane(__float_as_uint(x)));
}

// ---------------- kernel 1: selector softmax (fp64) + intensity (fp32) -----
// 2048 blocks x 256 thr; 2 tokens/block; dots split across lanes.
__global__ __launch_bounds__(256) void mlp_kernel(
    const float* __restrict__ x, const float* __restrict__ ctx,
    const float* __restrict__ w_sel1, const float* __restrict__ b_sel1,
    const float* __restrict__ w_sel2, const float* __restrict__ b_sel2,
    const float* __restrict__ w_int1, const float* __restrict__ b_int1,
    const float* __restrict__ w_int2, const float* __restrict__ b_int2,
    double* __restrict__ pw64, float* __restrict__ pw32,
    double* __restrict__ it64, float* __restrict__ it32)
{
    __shared__ double comb[2][256];
    __shared__ double h1[2][32];
    __shared__ float ipart[2][2];
    const int tid = threadIdx.x;
    const int tok0 = blockIdx.x * 2;
    const int t = tid >> 7, local = tid & 127;

    for (int r = 0; r < 2; ++r) {
        int idx = tid + r * 256;
        int tk = idx >> 8, i = idx & 255;
        comb[tk][i] = (double)((i < 128) ? x[(tok0 + tk) * 128 + i]
                                         : ctx[(tok0 + tk) * 128 + (i - 128)]);
    }
    __syncthreads();

    {   // sel1 (fp64): 32 units x 4 slices of 64
        int u = local >> 2, sl = local & 3;
        int i0 = sl * 64;
        double s0 = (sl == 0) ? (double)b_sel1[u] : 0.0, s1 = 0.0;
        for (int i = 0; i < 64; i += 2) {
            s0 = fma(comb[t][i0 + i],     (double)w_sel1[(i0 + i) * 32 + u],     s0);
            s1 = fma(comb[t][i0 + i + 1], (double)w_sel1[(i0 + i + 1) * 32 + u], s1);
        }
        double s = s0 + s1;
        s += __shfl_xor(s, 1);
        s += __shfl_xor(s, 2);
        if (sl == 0) h1[t][u] = gelu64(s);
    }
    {   // int1 (fp32): 64 units x 2 slices of 128; then reduce 64 units.
        // Intensity is a uniform positive per-token scale: top-k ranking,
        // threshold set and k are invariant to it -> fp32 is exact-safe.
        int u = local >> 1, sl = local & 1;
        int i0 = sl * 128;
        float a0 = (sl == 0) ? b_int1[u] : 0.0f, a1 = 0.0f, a2 = 0.0f, a3 = 0.0f;
        for (int i = 0; i < 128; i += 4) {
            a0 = fmaf((float)comb[t][i0 + i],     w_int1[(i0 + i) * 64 + u],     a0);
            a1 = fmaf((float)comb[t][i0 + i + 1], w_int1[(i0 + i + 1) * 64 + u], a1);
            a2 = fmaf((float)comb[t][i0 + i + 2], w_int1[(i0 + i + 2) * 64 + u], a2);
            a3 = fmaf((float)comb[t][i0 + i + 3], w_int1[(i0 + i + 3) * 64 + u], a3);
        }
        float s = (a0 + a1) + (a2 + a3);
        s += __shfl_xor(s, 1);
        float val = (sl == 0) ? gelu32(s) * w_int2[u] : 0.0f;
        for (int off = 2; off <= 32; off <<= 1)
            val += __shfl_xor(val, off);
        val += __shfl_xor(val, 1);   // sl==1 lanes carry 0; each unit counted once
        if ((local & 63) == 0) ipart[t][local >> 6] = val;
    }
    __syncthreads();

    if (tid < 32) {   // sel2 + softmax over P=16 (fp64)
        int t2 = tid >> 4, u = tid & 15;
        double z = (double)b_sel2[u];
        for (int j = 0; j < 32; ++j)
            z = fma(h1[t2][j], (double)w_sel2[j * 16 + u], z);
        double m = z;
        for (int off = 8; off >= 1; off >>= 1) m = fmax(m, __shfl_xor(m, off));
        double e = exp(z - m);
        double ssum = e;
        for (int off = 8; off >= 1; off >>= 1) ssum += __shfl_xor(ssum, off);
        double pwv = e / ssum;
        pw64[(tok0 + t2) * 16 + u] = pwv;
        pw32[(tok0 + t2) * 16 + u] = (float)pwv;
    } else if (tid < 34) {   // intensity finish (fp32)
        int t3 = tid - 32;
        float iv = sigmoid32(ipart[t3][0] + ipart[t3][1] + b_int2[0]);
        it64[tok0 + t3] = (double)iv;
        it32[tok0 + t3] = iv;
    }
}

// ---------------- kernel 2a: x.mean(axis=1) partial sums -------------------
__global__ __launch_bounds__(256) void win_part_kernel(
    const float* __restrict__ x, double* __restrict__ wpart)
{
    __shared__ double red[2][128];
    const int tid = threadIdx.x;
    const int b = blockIdx.x >> 4, chunk = blockIdx.x & 15;
    int i = tid & 127, h = tid >> 7;
    double a0 = 0.0, a1 = 0.0;
    int s0 = b * S_ + chunk * 64 + h * 32;
    for (int j = 0; j < 32; j += 2) {
        a0 += (double)x[(s0 + j) * 128 + i];
        a1 += (double)x[(s0 + j + 1) * 128 + i];
    }
    red[h][i] = a0 + a1;
    __syncthreads();
    if (tid < 128)
        wpart[(b * 16 + chunk) * 128 + tid] = red[0][tid] + red[1][tid];
}

// ---------------- kernel 2b: finish window MLP -----------------------------
__global__ __launch_bounds__(256) void win_fin_kernel(
    const double* __restrict__ wpart,
    const float* __restrict__ w_win1, const float* __restrict__ b_win1,
    const float* __restrict__ w_win2, const float* __restrict__ b_win2,
    double* __restrict__ win_out)
{
    __shared__ double xm[4][128];
    const int tid = threadIdx.x;
    const int b = tid >> 6, lane = tid & 63;
    for (int r = 0; r < 2; ++r) {
        int i = lane + r * 64;
        double s = 0.0;
        for (int c = 0; c < 16; ++c)
            s += wpart[(b * 16 + c) * 128 + i];
        xm[b][i] = s * (1.0 / 1024.0);
    }
    __syncthreads();
    {
        int u = lane;
        double s0 = (double)b_win1[u], s1 = 0.0;
        for (int i = 0; i < 128; i += 2) {
            s0 = fma(xm[b][i],     (double)w_win1[i * 64 + u],       s0);
            s1 = fma(xm[b][i + 1], (double)w_win1[(i + 1) * 64 + u], s1);
        }
        double c = gelu64(s0 + s1) * (double)w_win2[u];
        for (int off = 32; off >= 1; off >>= 1) c += __shfl_xor(c, off);
        if (lane == 0)
            win_out[b] = sigmoid64(c + (double)b_win2[0]) * 3840.0 + 256.0;
    }
}

// ---------------- kernel 3: fp32 flow + histogram top-k + masked write -----
// 2048 blocks x 512 thr; 2 tokens/block, 32 fp32 values/thread/token.
__global__ __launch_bounds__(512, 4) void flow_kernel(
    const float* __restrict__ patterns,
    const double* __restrict__ pw64, const float* __restrict__ pw32,
    const double* __restrict__ it64, const float* __restrict__ it32,
    const double* __restrict__ win,
    float* __restrict__ out)
{
    __shared__ unsigned hist[2][NB];
    __shared__ unsigned flagBits[2][512];
    __shared__ unsigned listIdx[2][CAPL];
    __shared__ double listVal[2][CAPL];
    __shared__ float smax[2][8];
    __shared__ int sred[8];
    __shared__ int bcastB[2];
    __shared__ unsigned listCnt[2];

    const int tid = threadIdx.x;
    const int lane = tid & 63, wv = tid >> 6;
    const int t0 = blockIdx.x * 2, t1 = t0 + 1;

    // zero LDS (hist + flags + counters)
    for (int r = tid; r < 2 * NB; r += 512) hist[r >> 9][r & (NB - 1)] = 0;
    for (int r = tid; r < 1024; r += 512) flagBits[r >> 9][r & 511] = 0;
    if (tid < 2) listCnt[tid] = 0;

    // k = max(1, floor(16384 * 0.1 * mean(window/4096)))  (np fp64 order)
    double w0 = win[0] * (1.0 / 4096.0), w1 = win[1] * (1.0 / 4096.0);
    double w2 = win[2] * (1.0 / 4096.0), w3 = win[3] * (1.0 / 4096.0);
    double mean = (((w0 + w1) + w2) + w3) * 0.25;
    double kd = floor(16384.0 * (0.1 * mean));
    int k = (kd < 1.0) ? 1 : (int)kd;

    float qw0[16], qw1[16];
#pragma unroll
    for (int p = 0; p < 16; ++p) {
        qw0[p] = rfl(pw32[t0 * 16 + p]);
        qw1[p] = rfl(pw32[t1 * 16 + p]);
    }
    float i0 = rfl(it32[t0]), i1 = rfl(it32[t1]);

    // value loop: explicit 8-load batches so 8 global_load_dwordx4 are in
    // flight before the dependent FMA group (latency hiding; r4 compiled to
    // ~4-load batches at VGPR=64 and sat at 30% VALUBusy).
    const v4f* pat4 = (const v4f*)patterns;
    v4f v0[8], v1[8];
#pragma unroll
    for (int c = 0; c < 8; ++c) {
        int grp = c * 512 + tid;
        v4f a0 = (v4f)(0.0f), a1 = (v4f)(0.0f);
        v4f pp[8];
#pragma unroll
        for (int p = 0; p < 8; ++p) pp[p] = pat4[p * 4096 + grp];
#pragma unroll
        for (int p = 0; p < 8; ++p) { a0 += qw0[p] * pp[p]; a1 += qw1[p] * pp[p]; }
#pragma unroll
        for (int p = 0; p < 8; ++p) pp[p] = pat4[(8 + p) * 4096 + grp];
#pragma unroll
        for (int p = 0; p < 8; ++p) { a0 += qw0[8 + p] * pp[p]; a1 += qw1[8 + p] * pp[p]; }
        v0[c] = a0 * i0;
        v1[c] = a1 * i1;
    }

    // per-token max |v|
    float mx0 = 0.0f, mx1 = 0.0f;
#pragma unroll
    for (int c = 0; c < 8; ++c) {
        mx0 = fmaxf(mx0, fmaxf(fmaxf(fabsf(v0[c].x), fabsf(v0[c].y)),
                               fmaxf(fabsf(v0[c].z), fabsf(v0[c].w))));
        mx1 = fmaxf(mx1, fmaxf(fmaxf(fabsf(v1[c].x), fabsf(v1[c].y)),
                               fmaxf(fabsf(v1[c].z), fabsf(v1[c].w))));
    }
    for (int off = 32; off >= 1; off >>= 1) {
        mx0 = fmaxf(mx0, __shfl_xor(mx0, off));
        mx1 = fmaxf(mx1, __shfl_xor(mx1, off));
    }
    if (lane == 0) { smax[0][wv] = mx0; smax[1][wv] = mx1; }
    __syncthreads();   // #1: covers zeroing + smax
    mx0 = smax[0][0]; mx1 = smax[1][0];
#pragma unroll
    for (int w = 1; w < 8; ++w) {
        mx0 = fmaxf(mx0, smax[0][w]);
        mx1 = fmaxf(mx1, smax[1][w]);
    }
    int base0 = (int)(__float_as_uint(mx0) >> 17) - (NB - 1);
    int base1 = (int)(__float_as_uint(mx1) >> 17) - (NB - 1);
    if (base0 < 0) base0 = 0;
    if (base1 < 0) base1 = 0;

    // histogram (skip underflow bucket 0 — never contains the threshold)
#pragma unroll
    for (int c = 0; c < 8; ++c) {
#pragma unroll
        for (int q = 0; q < 4; ++q) {
            int b0 = (int)(__float_as_uint(fabsf(v0[c][q])) >> 17) - base0;
            if (b0 > 0) atomicAdd(&hist[0][b0 > NB - 1 ? NB - 1 : b0], 1u);
            int b1 = (int)(__float_as_uint(fabsf(v1[c][q])) >> 17) - base1;
            if (b1 > 0) atomicAdd(&hist[1][b1 > NB - 1 ? NB - 1 : b1], 1u);
        }
    }
    __syncthreads();   // #2

    // waves 0/1: suffix-scan to find bucket B = bucket of k-th largest
    if (wv < 2) {
        int t = wv;
        int sum8 = 0;
#pragma unroll
        for (int j = 0; j < 8; ++j) sum8 += (int)hist[t][lane * 8 + j];
        int suffix = sum8;
        for (int off = 1; off <= 32; off <<= 1) {
            int other = __shfl_down(suffix, off);
            if (lane + off < 64) suffix += other;
        }
        int sufNext = __shfl_down(suffix, 1);
        if (lane == 63) sufNext = 0;
        unsigned long long msk = __ballot(suffix >= k);
        int Lstar = (msk == 0) ? 0 : (63 - __clzll(msk));
        if (lane == Lstar) {
            int cnt = sufNext, B = Lstar * 8;
            for (int j = 7; j >= 0; --j) {
                cnt += (int)hist[t][Lstar * 8 + j];
                if (cnt >= k) { B = Lstar * 8 + j; break; }
            }
            bcastB[t] = B;
        }
    }
    __syncthreads();   // #3

    int B0 = bcastB[0], B1 = bcastB[1];
    float loF0 = (B0 + base0) ? __uint_as_float((unsigned)(B0 + base0) << 17) : 0.0f;
    float hiF0 = __uint_as_float((unsigned)(B0 + base0 + 1) << 17);
    float loF1 = (B1 + base1) ? __uint_as_float((unsigned)(B1 + base1) << 17) : 0.0f;
    float hiF1 = __uint_as_float((unsigned)(B1 + base1 + 1) << 17);

    // margins: E bounds |v32 - true64|, same constants as rounds 3/4 (passed)
    float E0 = 3e-6f * i0, E1 = 3e-6f * i1;
    float loCut0 = loF0 - 2.0f * E0, hiCut0 = hiF0 + 2.0f * E0;
    float loCut1 = loF1 - 2.0f * E1, hiCut1 = hiF1 + 2.0f * E1;

    // sure-in count + candidate collection
    int ns0 = 0, ns1 = 0;
#pragma unroll
    for (int c = 0; c < 8; ++c) {
#pragma unroll
        for (int q = 0; q < 4; ++q) {
            unsigned e = (unsigned)(4 * (c * 512 + tid) + q);
            float a0 = fabsf(v0[c][q]);
            if (a0 >= hiCut0) ns0++;
            else if (a0 >= loCut0) {
                unsigned pos = atomicAdd(&listCnt[0], 1u);
                if (pos < CAPL) listIdx[0][pos] = e;
            }
            float a1 = fabsf(v1[c][q]);
            if (a1 >= hiCut1) ns1++;
            else if (a1 >= loCut1) {
                unsigned pos = atomicAdd(&listCnt[1], 1u);
                if (pos < CAPL) listIdx[1][pos] = e;
            }
        }
    }
    {
        int pk = ns0 | (ns1 << 16);   // ns <= 32/thread -> wave sum <= 2048, fits
#pragma unroll
        for (int off = 32; off >= 1; off >>= 1) pk += __shfl_xor(pk, off);
        if (lane == 0) sred[wv] = pk;
    }
    __syncthreads();   // #4
    int tot = 0;
#pragma unroll
    for (int w = 0; w < 8; ++w) tot += sred[w];
    int m0 = k - (tot & 0xffff), m1 = k - (tot >> 16);
    int c0n = (int)(listCnt[0] < CAPL ? listCnt[0] : CAPL);
    int c1n = (int)(listCnt[1] < CAPL ? listCnt[1] : CAPL);

    // fp64-exact values for candidates (matches np ranking to ~1e-15;
    // intensity factor is uniform per token -> ranking-invariant)
    double itt0 = it64[t0], itt1 = it64[t1];
    int totL = c0n + c1n;
    for (int g = tid; g < totL; g += 512) {
        int tk = (g >= c0n);
        int e = tk ? (g - c0n) : g;
        unsigned idx = listIdx[tk][e];
        const double* pwp = pw64 + (tk ? t1 : t0) * 16;
        double s = 0.0;
#pragma unroll
        for (int p = 0; p < 16; ++p)
            s = fma(pwp[p], (double)patterns[p * D_ + idx], s);
        listVal[tk][e] = fabs(s * (tk ? itt1 : itt0));
    }
    __syncthreads();   // #5
    // rank within list; keep iff (#strictly-greater) < m   [tie-correct]
    for (int g = tid; g < totL; g += 512) {
        int tk = (g >= c0n);
        int e = tk ? (g - c0n) : g;
        double my = listVal[tk][e];
        int cnt = tk ? c1n : c0n, m = tk ? m1 : m0;
        int r = 0;
        for (int j = 0; j < cnt; ++j) r += (listVal[tk][j] > my);
        if (r < m) {
            unsigned idx = listIdx[tk][e];
            atomicOr(&flagBits[tk][idx >> 5], 1u << (idx & 31));
        }
    }
    __syncthreads();   // #6

    // masked write
    v4f* o0p = (v4f*)(out + (size_t)t0 * D_);
    v4f* o1p = (v4f*)(out + (size_t)t1 * D_);
#pragma unroll
    for (int c = 0; c < 8; ++c) {
        int grp = c * 512 + tid;
        v4f r0, r1;
#pragma unroll
        for (int q = 0; q < 4; ++q) {
            unsigned e = (unsigned)(4 * grp + q);
            float av = fabsf(v0[c][q]);
            bool keep = (av >= hiCut0);
            if (!keep && av >= loCut0) keep = (flagBits[0][e >> 5] >> (e & 31)) & 1u;
            r0[q] = keep ? v0[c][q] : 0.0f;
            av = fabsf(v1[c][q]);
            keep = (av >= hiCut1);
            if (!keep && av >= loCut1) keep = (flagBits[1][e >> 5] >> (e & 31)) & 1u;
            r1[q] = keep ? v1[c][q] : 0.0f;
        }
        __builtin_nontemporal_store(r0, &o0p[grp]);
        __builtin_nontemporal_store(r1, &o1p[grp]);
    }
}

extern "C" void kernel_launch(void* const* d_in, const int* in_sizes, int n_in,
                              void* d_out, int out_size, void* d_ws, size_t ws_size,
                              hipStream_t stream) {
    const float* x        = (const float*)d_in[0];
    const float* ctx      = (const float*)d_in[1];
    const float* patterns = (const float*)d_in[2];
    const float* w_sel1   = (const float*)d_in[3];
    const float* b_sel1   = (const float*)d_in[4];
    const float* w_sel2   = (const float*)d_in[5];
    const float* b_sel2   = (const float*)d_in[6];
    const float* w_int1   = (const float*)d_in[7];
    const float* b_int1   = (const float*)d_in[8];
    const float* w_int2   = (const float*)d_in[9];
    const float* b_int2   = (const float*)d_in[10];
    const float* w_win1   = (const float*)d_in[11];
    const float* b_win1   = (const float*)d_in[12];
    const float* w_win2   = (const float*)d_in[13];
    const float* b_win2   = (const float*)d_in[14];

    double* ws    = (double*)d_ws;
    double* win   = ws;                   // 8 doubles reserved
    double* pw64  = ws + 8;               // 65536
    double* it64  = pw64 + 65536;         // 4096
    double* wpart = it64 + 4096;          // 8192
    float*  pw32  = (float*)(wpart + 8192);  // 65536 floats
    float*  it32  = pw32 + 65536;            // 4096 floats
    float*  out   = (float*)d_out;

    hipLaunchKernelGGL(mlp_kernel, dim3(2048), dim3(256), 0, stream,
                       x, ctx, w_sel1, b_sel1, w_sel2, b_sel2,
                       w_int1, b_int1, w_int2, b_int2, pw64, pw32, it64, it32);
    hipLaunchKernelGGL(win_part_kernel, dim3(64), dim3(256), 0, stream, x, wpart);
    hipLaunchKernelGGL(win_fin_kernel, dim3(1), dim3(256), 0, stream,
                       wpart, w_win1, b_win1, w_win2, b_win2, win);
    hipLaunchKernelGGL(flow_kernel, dim3(2048), dim3(512), 0, stream,
                       patterns, pw64, pw32, it64, it32, win, out);
}